// Round 3
// baseline (956.981 us; speedup 1.0000x reference)
//
#include <hip/hip_runtime.h>
#include <math.h>

#define N_NODES 50000
#define N_EDGES 500000
#define EP (N_EDGES + N_NODES)   // edges + self loops = 550000
#define IN_F 128
#define HID 64
#define HEADS 4
#define ZD (HEADS * HID)         // 256
#define G_B 16
#define OUT_F 326000
#define NEG 0.2f
#define SCAN_BLK 256
#define NBLK_SCAN ((N_NODES + SCAN_BLK - 1) / SCAN_BLK)   // 196
#define CAP 64                   // LDS-stash cap per dst (deg > CAP -> slow path)
#define EVS 72                   // per-head LDS stride
#define ZNPB 16                  // nodes per block in k_z / k_emb

__device__ __forceinline__ float bcast(float v, int lane) {
    return __int_as_float(__builtin_amdgcn_readlane(__float_as_int(v), lane));
}

// ---------------- init ----------------
__global__ void k_init(int* counts, int* cursor, float* pool, float* pool_cnt) {
    int i = blockIdx.x * 256 + threadIdx.x;
    if (i < N_NODES) { counts[i] = 1; cursor[i] = 0; }
    if (i < G_B * HID) pool[i] = 0.f;
    if (i < G_B) pool_cnt[i] = 0.f;
}

__global__ void k_count(const int* __restrict__ ei, int* __restrict__ counts) {
    int i = blockIdx.x * 256 + threadIdx.x;
    if (i < N_EDGES) atomicAdd(&counts[ei[N_EDGES + i]], 1);
}

__global__ void k_scan1(const int* __restrict__ counts, int* __restrict__ tmp,
                        int* __restrict__ partial) {
    __shared__ int s[SCAN_BLK];
    int t = threadIdx.x;
    int i = blockIdx.x * SCAN_BLK + t;
    int v = (i < N_NODES) ? counts[i] : 0;
    s[t] = v;
    __syncthreads();
    for (int off = 1; off < SCAN_BLK; off <<= 1) {
        int a = (t >= off) ? s[t - off] : 0;
        __syncthreads();
        s[t] += a;
        __syncthreads();
    }
    if (i < N_NODES) tmp[i] = s[t];
    if (t == SCAN_BLK - 1) partial[blockIdx.x] = s[t];
}

__global__ void k_scan2(int* partial) {
    __shared__ int s[SCAN_BLK];
    int t = threadIdx.x;
    int v = (t < NBLK_SCAN) ? partial[t] : 0;
    s[t] = v;
    __syncthreads();
    for (int off = 1; off < SCAN_BLK; off <<= 1) {
        int a = (t >= off) ? s[t - off] : 0;
        __syncthreads();
        s[t] += a;
        __syncthreads();
    }
    if (t < NBLK_SCAN) partial[t] = s[t] - v;   // exclusive
}

__global__ void k_scan3(const int* __restrict__ tmp, const int* __restrict__ counts,
                        const int* __restrict__ partial, int* __restrict__ offsets) {
    int i = blockIdx.x * 256 + threadIdx.x;
    if (i < N_NODES) offsets[i] = tmp[i] - counts[i] + partial[i >> 8];
    if (i == 0) offsets[N_NODES] = EP;
}

__global__ void k_fill(const int* __restrict__ ei, const int* __restrict__ offsets,
                       int* __restrict__ cursor, int* __restrict__ edge_src) {
    int i = blockIdx.x * 256 + threadIdx.x;
    if (i >= EP) return;
    int s, d;
    if (i < N_EDGES) { s = ei[i]; d = ei[N_EDGES + i]; }
    else             { s = d = i - N_EDGES; }
    int pos = offsets[d] + atomicAdd(&cursor[d], 1);
    edge_src[pos] = s;
}

// ---------------- node embedding: W column in regs, x broadcast via readlane ----
// 1 wave per block, 16 nodes; K=128 chunked in two 64-wide passes.
__global__ void k_emb(const float* __restrict__ x, const float* __restrict__ W,
                      const float* __restrict__ b, float* __restrict__ h) {
    int l = threadIdx.x;                         // 64 threads
    int n0 = blockIdx.x * ZNPB;
    float acc[ZNPB];
    #pragma unroll
    for (int n = 0; n < ZNPB; n++) acc[n] = 0.f;
    #pragma unroll
    for (int kc = 0; kc < IN_F; kc += 64) {
        float Wc[64];
        #pragma unroll
        for (int k = 0; k < 64; k++) Wc[k] = W[(kc + k) * HID + l];
        float xr[ZNPB];
        #pragma unroll
        for (int n = 0; n < ZNPB; n++) xr[n] = x[(size_t)(n0 + n) * IN_F + kc + l];
        #pragma unroll
        for (int k = 0; k < 64; k++) {
            float wv = Wc[k];
            #pragma unroll
            for (int n = 0; n < ZNPB; n++)
                acc[n] = fmaf(bcast(xr[n], k), wv, acc[n]);
        }
    }
    float bv = b[l];
    #pragma unroll
    for (int n = 0; n < ZNPB; n++) h[(size_t)(n0 + n) * HID + l] = acc[n] + bv;
}

// ---------------- z = h @ W fused with attention logits --------------
// 256 threads: wave w = head w (cols w*64..w*64+63). 16 nodes per block.
// W column held in 64 VGPRs; h broadcast via v_readlane.
__global__ void k_z(const float* __restrict__ h, const float* __restrict__ W,
                    const float* __restrict__ a_src, const float* __restrict__ a_dst,
                    float* __restrict__ z, float* __restrict__ al_s,
                    float* __restrict__ al_d) {
    int t = threadIdx.x;
    int w = t >> 6, l = t & 63;
    int n0 = blockIdx.x * ZNPB;
    int c = w * HID + l;
    float Wc[HID];
    #pragma unroll
    for (int k = 0; k < HID; k++) Wc[k] = W[k * ZD + c];
    float hr[ZNPB];
    #pragma unroll
    for (int n = 0; n < ZNPB; n++) hr[n] = h[(size_t)(n0 + n) * HID + l];
    float acc[ZNPB];
    #pragma unroll
    for (int n = 0; n < ZNPB; n++) acc[n] = 0.f;
    #pragma unroll
    for (int k = 0; k < HID; k++) {
        float wv = Wc[k];
        #pragma unroll
        for (int n = 0; n < ZNPB; n++)
            acc[n] = fmaf(bcast(hr[n], k), wv, acc[n]);
    }
    float av = a_src[w * HID + l];
    float dv = a_dst[w * HID + l];
    #pragma unroll
    for (int n = 0; n < ZNPB; n++) {
        z[(size_t)(n0 + n) * ZD + c] = acc[n];
        float ps = acc[n] * av;
        float pd = acc[n] * dv;
        #pragma unroll
        for (int o = 32; o > 0; o >>= 1) {
            ps += __shfl_xor(ps, o);
            pd += __shfl_xor(pd, o);
        }
        if (l == 0) {
            al_s[(n0 + n) * HEADS + w] = ps;
            al_d[(n0 + n) * HEADS + w] = pd;
        }
    }
}

__device__ __forceinline__ float lrelu(float v) { return v > 0.f ? v : NEG * v; }

// ---------------- fused softmax + aggregate: ONE WAVE PER DST ----------------
__global__ void k_agg(const int* __restrict__ offsets, const int* __restrict__ edge_src,
                      const float* __restrict__ al_s, const float* __restrict__ al_d,
                      const float* __restrict__ z, const float* __restrict__ b,
                      float* __restrict__ h) {
    __shared__ float evb[4][HEADS * EVS];   // per wave: per-head alpha stash
    __shared__ int   sb[4][CAP];            // per wave: src idx stash
    int t  = threadIdx.x;
    int w  = t >> 6;
    int l  = t & 63;
    int hd = l >> 4;
    int j  = l & 15;
    int d  = blockIdx.x * 4 + w;

    int start = __builtin_amdgcn_readfirstlane(offsets[d]);
    int end   = __builtin_amdgcn_readfirstlane(offsets[d + 1]);
    int deg   = end - start;
    float al_dd = al_d[d * HEADS + hd];

    // phase 1: per-lane online softmax over strided edges; stash src + ev
    float m = -INFINITY, ssum = 0.f;
    for (int i = start + j; i < end; i += 16) {
        int s = edge_src[i];
        int slot = i - start;
        if (hd == 0 && slot < CAP) sb[w][slot] = s;
        float ev = lrelu(al_s[s * HEADS + hd] + al_dd);
        if (slot < CAP) evb[w][hd * EVS + slot] = ev;
        float nm = fmaxf(m, ev);
        ssum = ssum * __expf(m - nm) + __expf(ev - nm);
        m = nm;
    }
    float M = m;
    for (int o = 8; o > 0; o >>= 1) M = fmaxf(M, __shfl_xor(M, o));
    float S = ssum * __expf(m - M);
    for (int o = 8; o > 0; o >>= 1) S += __shfl_xor(S, o);
    float inv = 1.f / (S + 1e-16f);
    int stop = deg < CAP ? deg : CAP;
    for (int slot = j; slot < stop; slot += 16)
        evb[w][hd * EVS + slot] = __expf(evb[w][hd * EVS + slot] - M) * inv;

    // phase 2: weighted float4 gather of full z rows, x2 unrolled for MLP
    float4 acc = {0.f, 0.f, 0.f, 0.f};
    if (deg <= CAP) {
        float4 acc2 = {0.f, 0.f, 0.f, 0.f};
        int slot = 0;
        int lim = deg & ~1;
        for (; slot < lim; slot += 2) {
            int s0 = sb[w][slot];
            int s1 = sb[w][slot + 1];
            float a0 = evb[w][hd * EVS + slot];
            float a1 = evb[w][hd * EVS + slot + 1];
            float4 z0 = *(const float4*)&z[(size_t)s0 * ZD + l * 4];
            float4 z1 = *(const float4*)&z[(size_t)s1 * ZD + l * 4];
            acc.x  += a0 * z0.x; acc.y  += a0 * z0.y;
            acc.z  += a0 * z0.z; acc.w  += a0 * z0.w;
            acc2.x += a1 * z1.x; acc2.y += a1 * z1.y;
            acc2.z += a1 * z1.z; acc2.w += a1 * z1.w;
        }
        if (slot < deg) {
            int s0 = sb[w][slot];
            float a0 = evb[w][hd * EVS + slot];
            float4 z0 = *(const float4*)&z[(size_t)s0 * ZD + l * 4];
            acc.x += a0 * z0.x; acc.y += a0 * z0.y;
            acc.z += a0 * z0.z; acc.w += a0 * z0.w;
        }
        acc.x += acc2.x; acc.y += acc2.y; acc.z += acc2.z; acc.w += acc2.w;
    } else {
        // rare slow path: recompute alpha per edge
        for (int i = start; i < end; i++) {
            int s = __builtin_amdgcn_readfirstlane(edge_src[i]);
            float ev = lrelu(al_s[s * HEADS + hd] + al_dd);
            float alpha = __expf(ev - M) * inv;
            float4 zr = *(const float4*)&z[(size_t)s * ZD + l * 4];
            acc.x += alpha * zr.x; acc.y += alpha * zr.y;
            acc.z += alpha * zr.z; acc.w += alpha * zr.w;
        }
    }
    // head mean: sum across the 4 head groups
    acc.x += __shfl_xor(acc.x, 16); acc.y += __shfl_xor(acc.y, 16);
    acc.z += __shfl_xor(acc.z, 16); acc.w += __shfl_xor(acc.w, 16);
    acc.x += __shfl_xor(acc.x, 32); acc.y += __shfl_xor(acc.y, 32);
    acc.z += __shfl_xor(acc.z, 32); acc.w += __shfl_xor(acc.w, 32);
    if (l < 16) {
        float4 bv = *(const float4*)&b[l * 4];
        float4 r;
        r.x = fmaxf(acc.x * 0.25f + bv.x, 0.f);
        r.y = fmaxf(acc.y * 0.25f + bv.y, 0.f);
        r.z = fmaxf(acc.z * 0.25f + bv.z, 0.f);
        r.w = fmaxf(acc.w * 0.25f + bv.w, 0.f);
        *(float4*)&h[(size_t)d * HID + l * 4] = r;
    }
}

// ---------------- global mean pool (batch is sorted) ----------------
__global__ void k_pool(const float* __restrict__ h, const int* __restrict__ batch,
                       float* __restrict__ pool, float* __restrict__ pool_cnt) {
    int f = threadIdx.x;           // 64 threads
    int n0 = blockIdx.x * 256;
    int n1 = n0 + 256;
    if (n1 > N_NODES) n1 = N_NODES;
    if (n0 >= n1) return;
    int curg = batch[n0];
    float acc = 0.f;
    int cnt = 0;
    for (int n = n0; n < n1; n++) {
        int g = batch[n];
        if (g != curg) {
            atomicAdd(&pool[curg * HID + f], acc);
            if (f == 0) atomicAdd(&pool_cnt[curg], (float)cnt);
            acc = 0.f; cnt = 0; curg = g;
        }
        acc += h[n * HID + f];
        cnt++;
    }
    atomicAdd(&pool[curg * HID + f], acc);
    if (f == 0) atomicAdd(&pool_cnt[curg], (float)cnt);
}

// ---------------- final FC: out = hg @ W_fc + b_fc ----------------
__global__ void k_fc(const float* __restrict__ pool, const float* __restrict__ pool_cnt,
                     const float* __restrict__ W_fc, const float* __restrict__ b_fc,
                     float* __restrict__ out) {
    __shared__ float hg[G_B * HID];
    int t = threadIdx.x;
    for (int i = t; i < G_B * HID; i += 256)
        hg[i] = pool[i] / fmaxf(pool_cnt[i / HID], 1.f);
    __syncthreads();
    int o = blockIdx.x * 256 + t;
    if (o >= OUT_F) return;
    float acc[G_B];
    float bo = b_fc[o];
    #pragma unroll
    for (int g = 0; g < G_B; g++) acc[g] = bo;
    for (int k = 0; k < HID; k++) {
        float w = W_fc[(size_t)k * OUT_F + o];
        #pragma unroll
        for (int g = 0; g < G_B; g++) acc[g] += hg[g * HID + k] * w;
    }
    #pragma unroll
    for (int g = 0; g < G_B; g++) out[(size_t)g * OUT_F + o] = acc[g];
}

extern "C" void kernel_launch(void* const* d_in, const int* in_sizes, int n_in,
                              void* d_out, int out_size, void* d_ws, size_t ws_size,
                              hipStream_t stream) {
    const float* x       = (const float*)d_in[0];
    const int*   ei      = (const int*)d_in[1];
    // d_in[2] edge_attr: unused by the reference forward
    const int*   batch   = (const int*)d_in[3];
    const float* W_emb   = (const float*)d_in[4];
    const float* b_emb   = (const float*)d_in[5];
    const float* W_gat   = (const float*)d_in[6];
    const float* att_src = (const float*)d_in[7];
    const float* att_dst = (const float*)d_in[8];
    const float* b_gat   = (const float*)d_in[9];
    const float* W_fc    = (const float*)d_in[10];
    const float* b_fc    = (const float*)d_in[11];
    float* out = (float*)d_out;

    char* p = (char*)d_ws;
    auto alloc = [&](size_t bytes) -> void* {
        void* r = (void*)p;
        p += (bytes + 255) & ~(size_t)255;
        return r;
    };
    float* h        = (float*)alloc((size_t)N_NODES * HID * 4);
    float* z        = (float*)alloc((size_t)N_NODES * ZD * 4);
    float* al_s     = (float*)alloc((size_t)N_NODES * HEADS * 4);
    float* al_d     = (float*)alloc((size_t)N_NODES * HEADS * 4);
    int*   counts   = (int*)alloc((size_t)N_NODES * 4);
    int*   offsets  = (int*)alloc((size_t)(N_NODES + 1) * 4);
    int*   cursor   = (int*)alloc((size_t)N_NODES * 4);
    int*   tmp      = (int*)alloc((size_t)N_NODES * 4);
    int*   partial  = (int*)alloc((size_t)SCAN_BLK * 4);
    int*   edge_src = (int*)alloc((size_t)EP * 4);
    float* pool     = (float*)alloc((size_t)G_B * HID * 4);
    float* pool_cnt = (float*)alloc((size_t)G_B * 4);

    // CSR build (once per launch; reused by all 3 layers)
    k_init <<<NBLK_SCAN, 256, 0, stream>>>(counts, cursor, pool, pool_cnt);
    k_count<<<(N_EDGES + 255) / 256, 256, 0, stream>>>(ei, counts);
    k_scan1<<<NBLK_SCAN, SCAN_BLK, 0, stream>>>(counts, tmp, partial);
    k_scan2<<<1, SCAN_BLK, 0, stream>>>(partial);
    k_scan3<<<NBLK_SCAN, 256, 0, stream>>>(tmp, counts, partial, offsets);
    k_fill <<<(EP + 255) / 256, 256, 0, stream>>>(ei, offsets, cursor, edge_src);

    // node embedding
    k_emb<<<N_NODES / ZNPB, 64, 0, stream>>>(x, W_emb, b_emb, h);

    // 3 GAT layers (k_att fused into k_z)
    for (int l = 0; l < 3; l++) {
        k_z  <<<N_NODES / ZNPB, 256, 0, stream>>>(h, W_gat + (size_t)l * HID * ZD,
                                                  att_src + (size_t)l * HEADS * HID,
                                                  att_dst + (size_t)l * HEADS * HID,
                                                  z, al_s, al_d);
        k_agg<<<N_NODES / 4, 256, 0, stream>>>(offsets, edge_src, al_s, al_d, z,
                                               b_gat + (size_t)l * HID, h);
    }

    // pooling + FC
    k_pool<<<NBLK_SCAN, 64, 0, stream>>>(h, batch, pool, pool_cnt);
    k_fc  <<<(OUT_F + 255) / 256, 256, 0, stream>>>(pool, pool_cnt, W_fc, b_fc, out);
}

// Round 4
// 669.237 us; speedup vs baseline: 1.4300x; 1.4300x over previous
//
#include <hip/hip_runtime.h>
#include <math.h>

#define N_NODES 50000
#define NPAD 50048               // 64 * 782, padded node count for tiled GEMMs
#define N_EDGES 500000
#define EP (N_EDGES + N_NODES)   // 550000
#define IN_F 128
#define HID 64
#define HEADS 4
#define ZD (HEADS * HID)         // 256
#define G_B 16
#define OUT_F 326000
#define NEG 0.2f
#define SCAN_BLK 256
#define NBLK_SCAN ((N_NODES + SCAN_BLK - 1) / SCAN_BLK)   // 196
#define CAP 64                   // LDS-stash cap per dst
#define EVS 72                   // per-head LDS stride
#define NT 64                    // node tile for GEMM kernels
#define HP (HID + 4)             // 68: padded k-stride (transposed b128 conflict-free)
#define XP (IN_F + 4)            // 132
#define TP 20                    // transpose stash row stride (16 + 4)

// ---------------- init ----------------
__global__ void k_init(int* counts, int* cursor, float* pool, float* pool_cnt) {
    int i = blockIdx.x * 256 + threadIdx.x;
    if (i < N_NODES) { counts[i] = 1; cursor[i] = 0; }
    if (i < G_B * HID) pool[i] = 0.f;
    if (i < G_B) pool_cnt[i] = 0.f;
}

__global__ void k_count(const int* __restrict__ ei, int* __restrict__ counts) {
    int i = blockIdx.x * 256 + threadIdx.x;
    if (i < N_EDGES) atomicAdd(&counts[ei[N_EDGES + i]], 1);
}

__global__ void k_scan1(const int* __restrict__ counts, int* __restrict__ tmp,
                        int* __restrict__ partial) {
    __shared__ int s[SCAN_BLK];
    int t = threadIdx.x;
    int i = blockIdx.x * SCAN_BLK + t;
    int v = (i < N_NODES) ? counts[i] : 0;
    s[t] = v;
    __syncthreads();
    for (int off = 1; off < SCAN_BLK; off <<= 1) {
        int a = (t >= off) ? s[t - off] : 0;
        __syncthreads();
        s[t] += a;
        __syncthreads();
    }
    if (i < N_NODES) tmp[i] = s[t];
    if (t == SCAN_BLK - 1) partial[blockIdx.x] = s[t];
}

__global__ void k_scan2(int* partial) {
    __shared__ int s[SCAN_BLK];
    int t = threadIdx.x;
    int v = (t < NBLK_SCAN) ? partial[t] : 0;
    s[t] = v;
    __syncthreads();
    for (int off = 1; off < SCAN_BLK; off <<= 1) {
        int a = (t >= off) ? s[t - off] : 0;
        __syncthreads();
        s[t] += a;
        __syncthreads();
    }
    if (t < NBLK_SCAN) partial[t] = s[t] - v;   // exclusive
}

__global__ void k_scan3(const int* __restrict__ tmp, const int* __restrict__ counts,
                        const int* __restrict__ partial, int* __restrict__ offsets) {
    int i = blockIdx.x * 256 + threadIdx.x;
    if (i < N_NODES) offsets[i] = tmp[i] - counts[i] + partial[i >> 8];
    if (i == 0) offsets[N_NODES] = EP;
}

__global__ void k_fill(const int* __restrict__ ei, const int* __restrict__ offsets,
                       int* __restrict__ cursor, int* __restrict__ edge_src) {
    int i = blockIdx.x * 256 + threadIdx.x;
    if (i >= EP) return;
    int s, d;
    if (i < N_EDGES) { s = ei[i]; d = ei[N_EDGES + i]; }
    else             { s = d = i - N_EDGES; }
    int pos = offsets[d] + atomicAdd(&cursor[d], 1);
    edge_src[pos] = s;
}

// ---------------- node embedding: lane=node, W via s_load, LDS-staged x ----
// block = 4 waves x 16 cols = all 64 out cols; 64 nodes per block.
__global__ __launch_bounds__(256) void k_emb(const float* __restrict__ x,
                                             const float* __restrict__ W,
                                             const float* __restrict__ b,
                                             float* __restrict__ h) {
    __shared__ float xs[NT * XP];        // 33792 B
    __shared__ float tr[4 * NT * TP];    // 20480 B
    int t = threadIdx.x;
    int w = __builtin_amdgcn_readfirstlane(t >> 6);   // uniform wave id
    int l = t & 63;
    int n0 = blockIdx.x * NT;
    int c0 = w * 16;

    // stage x tile [64 nodes][128 k], clamp tail rows
    #pragma unroll
    for (int i = 0; i < 8; i++) {
        int idx = i * 256 + t;           // 0..2047
        int r = idx >> 5;                // 32 float4 per row
        int q = idx & 31;
        int rg = n0 + r; if (rg >= N_NODES) rg = N_NODES - 1;
        float4 v = *(const float4*)&x[(size_t)rg * IN_F + q * 4];
        *(float4*)&xs[r * XP + q * 4] = v;
    }
    __syncthreads();

    float acc[16];
    #pragma unroll
    for (int j = 0; j < 16; j++) acc[j] = 0.f;
    const float* Wb = W + c0;            // uniform base
    #pragma unroll
    for (int k4 = 0; k4 < IN_F; k4 += 4) {
        float4 hv = *(const float4*)&xs[l * XP + k4];
        float hk[4] = {hv.x, hv.y, hv.z, hv.w};
        #pragma unroll
        for (int kk = 0; kk < 4; kk++) {
            #pragma unroll
            for (int j = 0; j < 16; j++)
                acc[j] = fmaf(hk[kk], Wb[(k4 + kk) * HID + j], acc[j]);
        }
    }
    const float* bb = b + c0;
    #pragma unroll
    for (int j = 0; j < 16; j++) acc[j] += bb[j];

    // transpose stash -> coalesced store
    float* trw = tr + w * NT * TP;
    #pragma unroll
    for (int j4 = 0; j4 < 16; j4 += 4) {
        float4 v = make_float4(acc[j4], acc[j4 + 1], acc[j4 + 2], acc[j4 + 3]);
        *(float4*)&trw[l * TP + j4] = v;
    }
    __syncthreads();
    int node = l >> 2, q = (l & 3) * 4;
    #pragma unroll
    for (int i = 0; i < 4; i++) {
        int nd = node + i * 16;
        float4 v = *(const float4*)&trw[nd * TP + q];
        *(float4*)&h[(size_t)(n0 + nd) * HID + c0 + q] = v;
    }
}

// ---------------- z = h @ W + fused attention logits --------------
// grid = 782 tiles x 4 col-groups; col-group cg == head cg.
__global__ __launch_bounds__(256) void k_z(const float* __restrict__ h,
                                           const float* __restrict__ W,
                                           const float* __restrict__ a_src,
                                           const float* __restrict__ a_dst,
                                           float* __restrict__ z,
                                           float* __restrict__ al_s,
                                           float* __restrict__ al_d) {
    __shared__ float hs[NT * HP];        // 17408 B
    __shared__ float tr[4 * NT * TP];    // 20480 B
    __shared__ float ps[4][NT], pd[4][NT];
    int t = threadIdx.x;
    int w = __builtin_amdgcn_readfirstlane(t >> 6);
    int l = t & 63;
    int tile = blockIdx.x >> 2;
    int cg = blockIdx.x & 3;             // head
    int n0 = tile * NT;
    int c0 = cg * 64 + w * 16;

    // stage h tile [64 nodes][64 k] (h is padded to NPAD rows)
    #pragma unroll
    for (int i = 0; i < 4; i++) {
        int idx = i * 256 + t;           // 0..1023
        int r = idx >> 4;                // 16 float4 per row
        int q = idx & 15;
        float4 v = *(const float4*)&h[(size_t)(n0 + r) * HID + q * 4];
        *(float4*)&hs[r * HP + q * 4] = v;
    }
    __syncthreads();

    float acc[16];
    #pragma unroll
    for (int j = 0; j < 16; j++) acc[j] = 0.f;
    const float* Wb = W + c0;            // uniform base
    #pragma unroll
    for (int k4 = 0; k4 < HID; k4 += 4) {
        float4 hv = *(const float4*)&hs[l * HP + k4];
        float hk[4] = {hv.x, hv.y, hv.z, hv.w};
        #pragma unroll
        for (int kk = 0; kk < 4; kk++) {
            #pragma unroll
            for (int j = 0; j < 16; j++)
                acc[j] = fmaf(hk[kk], Wb[(k4 + kk) * ZD + j], acc[j]);
        }
    }

    // attention logit partials (this wave covers 16 of head cg's 64 feats)
    const float* as = a_src + cg * HID + w * 16;
    const float* ad = a_dst + cg * HID + w * 16;
    float p_s = 0.f, p_d = 0.f;
    #pragma unroll
    for (int j = 0; j < 16; j++) {
        p_s = fmaf(acc[j], as[j], p_s);
        p_d = fmaf(acc[j], ad[j], p_d);
    }
    ps[w][l] = p_s; pd[w][l] = p_d;

    // transpose stash -> coalesced z store
    float* trw = tr + w * NT * TP;
    #pragma unroll
    for (int j4 = 0; j4 < 16; j4 += 4) {
        float4 v = make_float4(acc[j4], acc[j4 + 1], acc[j4 + 2], acc[j4 + 3]);
        *(float4*)&trw[l * TP + j4] = v;
    }
    __syncthreads();
    int node = l >> 2, q = (l & 3) * 4;
    #pragma unroll
    for (int i = 0; i < 4; i++) {
        int nd = node + i * 16;
        float4 v = *(const float4*)&trw[nd * TP + q];
        *(float4*)&z[(size_t)(n0 + nd) * ZD + c0 + q] = v;
    }
    if (t < NT) {
        float vs = ps[0][t] + ps[1][t] + ps[2][t] + ps[3][t];
        float vd = pd[0][t] + pd[1][t] + pd[2][t] + pd[3][t];
        al_s[(n0 + t) * HEADS + cg] = vs;
        al_d[(n0 + t) * HEADS + cg] = vd;
    }
}

__device__ __forceinline__ float lrelu(float v) { return v > 0.f ? v : NEG * v; }

// ---------------- fused softmax + aggregate: ONE WAVE PER DST ----------------
__global__ void k_agg(const int* __restrict__ offsets, const int* __restrict__ edge_src,
                      const float* __restrict__ al_s, const float* __restrict__ al_d,
                      const float* __restrict__ z, const float* __restrict__ b,
                      float* __restrict__ h) {
    __shared__ float evb[4][HEADS * EVS];   // per wave: per-head alpha stash
    __shared__ int   sb[4][CAP];            // per wave: src idx stash
    int t  = threadIdx.x;
    int w  = t >> 6;
    int l  = t & 63;
    int hd = l >> 4;
    int j  = l & 15;
    int d  = blockIdx.x * 4 + w;

    int start = __builtin_amdgcn_readfirstlane(offsets[d]);
    int end   = __builtin_amdgcn_readfirstlane(offsets[d + 1]);
    int deg   = end - start;
    float al_dd = al_d[d * HEADS + hd];

    // phase 1: per-lane online softmax over strided edges; stash src + ev
    float m = -INFINITY, ssum = 0.f;
    for (int i = start + j; i < end; i += 16) {
        int s = edge_src[i];
        int slot = i - start;
        if (hd == 0 && slot < CAP) sb[w][slot] = s;
        float ev = lrelu(al_s[s * HEADS + hd] + al_dd);
        if (slot < CAP) evb[w][hd * EVS + slot] = ev;
        float nm = fmaxf(m, ev);
        ssum = ssum * __expf(m - nm) + __expf(ev - nm);
        m = nm;
    }
    float M = m;
    for (int o = 8; o > 0; o >>= 1) M = fmaxf(M, __shfl_xor(M, o));
    float S = ssum * __expf(m - M);
    for (int o = 8; o > 0; o >>= 1) S += __shfl_xor(S, o);
    float inv = 1.f / (S + 1e-16f);
    int stop = deg < CAP ? deg : CAP;
    for (int slot = j; slot < stop; slot += 16)
        evb[w][hd * EVS + slot] = __expf(evb[w][hd * EVS + slot] - M) * inv;

    // phase 2: weighted float4 gather of full z rows, x4 unrolled for MLP
    int zoff = l * 4;
    float4 acc = {0.f, 0.f, 0.f, 0.f};
    if (deg <= CAP) {
        float4 a1 = {0,0,0,0}, a2 = {0,0,0,0}, a3 = {0,0,0,0};
        int slot = 0;
        for (; slot + 4 <= deg; slot += 4) {
            int s0 = sb[w][slot],     s1 = sb[w][slot + 1];
            int s2 = sb[w][slot + 2], s3 = sb[w][slot + 3];
            float w0 = evb[w][hd * EVS + slot];
            float w1 = evb[w][hd * EVS + slot + 1];
            float w2 = evb[w][hd * EVS + slot + 2];
            float w3 = evb[w][hd * EVS + slot + 3];
            float4 z0 = *(const float4*)&z[(size_t)s0 * ZD + zoff];
            float4 z1 = *(const float4*)&z[(size_t)s1 * ZD + zoff];
            float4 z2 = *(const float4*)&z[(size_t)s2 * ZD + zoff];
            float4 z3 = *(const float4*)&z[(size_t)s3 * ZD + zoff];
            acc.x += w0 * z0.x; acc.y += w0 * z0.y; acc.z += w0 * z0.z; acc.w += w0 * z0.w;
            a1.x  += w1 * z1.x; a1.y  += w1 * z1.y; a1.z  += w1 * z1.z; a1.w  += w1 * z1.w;
            a2.x  += w2 * z2.x; a2.y  += w2 * z2.y; a2.z  += w2 * z2.z; a2.w  += w2 * z2.w;
            a3.x  += w3 * z3.x; a3.y  += w3 * z3.y; a3.z  += w3 * z3.z; a3.w  += w3 * z3.w;
        }
        for (; slot < deg; slot++) {
            int s0 = sb[w][slot];
            float w0 = evb[w][hd * EVS + slot];
            float4 z0 = *(const float4*)&z[(size_t)s0 * ZD + zoff];
            acc.x += w0 * z0.x; acc.y += w0 * z0.y; acc.z += w0 * z0.z; acc.w += w0 * z0.w;
        }
        acc.x += a1.x + a2.x + a3.x;
        acc.y += a1.y + a2.y + a3.y;
        acc.z += a1.z + a2.z + a3.z;
        acc.w += a1.w + a2.w + a3.w;
    } else {
        for (int i = start; i < end; i++) {
            int s = __builtin_amdgcn_readfirstlane(edge_src[i]);
            float ev = lrelu(al_s[s * HEADS + hd] + al_dd);
            float alpha = __expf(ev - M) * inv;
            float4 zr = *(const float4*)&z[(size_t)s * ZD + zoff];
            acc.x += alpha * zr.x; acc.y += alpha * zr.y;
            acc.z += alpha * zr.z; acc.w += alpha * zr.w;
        }
    }
    // head mean across the 4 head groups
    acc.x += __shfl_xor(acc.x, 16); acc.y += __shfl_xor(acc.y, 16);
    acc.z += __shfl_xor(acc.z, 16); acc.w += __shfl_xor(acc.w, 16);
    acc.x += __shfl_xor(acc.x, 32); acc.y += __shfl_xor(acc.y, 32);
    acc.z += __shfl_xor(acc.z, 32); acc.w += __shfl_xor(acc.w, 32);
    if (l < 16) {
        float4 bv = *(const float4*)&b[l * 4];
        float4 r;
        r.x = fmaxf(acc.x * 0.25f + bv.x, 0.f);
        r.y = fmaxf(acc.y * 0.25f + bv.y, 0.f);
        r.z = fmaxf(acc.z * 0.25f + bv.z, 0.f);
        r.w = fmaxf(acc.w * 0.25f + bv.w, 0.f);
        *(float4*)&h[(size_t)d * HID + l * 4] = r;
    }
}

// ---------------- global mean pool (batch is sorted) ----------------
__global__ void k_pool(const float* __restrict__ h, const int* __restrict__ batch,
                       float* __restrict__ pool, float* __restrict__ pool_cnt) {
    int f = threadIdx.x;           // 64 threads
    int n0 = blockIdx.x * 256;
    int n1 = n0 + 256;
    if (n1 > N_NODES) n1 = N_NODES;
    if (n0 >= n1) return;
    int curg = batch[n0];
    float acc = 0.f;
    int cnt = 0;
    for (int n = n0; n < n1; n++) {
        int g = batch[n];
        if (g != curg) {
            atomicAdd(&pool[curg * HID + f], acc);
            if (f == 0) atomicAdd(&pool_cnt[curg], (float)cnt);
            acc = 0.f; cnt = 0; curg = g;
        }
        acc += h[n * HID + f];
        cnt++;
    }
    atomicAdd(&pool[curg * HID + f], acc);
    if (f == 0) atomicAdd(&pool_cnt[curg], (float)cnt);
}

// ---------------- final FC: out = hg @ W_fc + b_fc ----------------
__global__ void k_fc(const float* __restrict__ pool, const float* __restrict__ pool_cnt,
                     const float* __restrict__ W_fc, const float* __restrict__ b_fc,
                     float* __restrict__ out) {
    __shared__ float hg[G_B * HID];
    int t = threadIdx.x;
    for (int i = t; i < G_B * HID; i += 256)
        hg[i] = pool[i] / fmaxf(pool_cnt[i / HID], 1.f);
    __syncthreads();
    int o = blockIdx.x * 256 + t;
    if (o >= OUT_F) return;
    float acc[G_B];
    float bo = b_fc[o];
    #pragma unroll
    for (int g = 0; g < G_B; g++) acc[g] = bo;
    for (int k = 0; k < HID; k++) {
        float w = W_fc[(size_t)k * OUT_F + o];
        #pragma unroll
        for (int g = 0; g < G_B; g++) acc[g] += hg[g * HID + k] * w;
    }
    #pragma unroll
    for (int g = 0; g < G_B; g++) out[(size_t)g * OUT_F + o] = acc[g];
}

extern "C" void kernel_launch(void* const* d_in, const int* in_sizes, int n_in,
                              void* d_out, int out_size, void* d_ws, size_t ws_size,
                              hipStream_t stream) {
    const float* x       = (const float*)d_in[0];
    const int*   ei      = (const int*)d_in[1];
    // d_in[2] edge_attr: unused by the reference forward
    const int*   batch   = (const int*)d_in[3];
    const float* W_emb   = (const float*)d_in[4];
    const float* b_emb   = (const float*)d_in[5];
    const float* W_gat   = (const float*)d_in[6];
    const float* att_src = (const float*)d_in[7];
    const float* att_dst = (const float*)d_in[8];
    const float* b_gat   = (const float*)d_in[9];
    const float* W_fc    = (const float*)d_in[10];
    const float* b_fc    = (const float*)d_in[11];
    float* out = (float*)d_out;

    char* p = (char*)d_ws;
    auto alloc = [&](size_t bytes) -> void* {
        void* r = (void*)p;
        p += (bytes + 255) & ~(size_t)255;
        return r;
    };
    float* h        = (float*)alloc((size_t)NPAD * HID * 4);
    float* z        = (float*)alloc((size_t)NPAD * ZD * 4);
    float* al_s     = (float*)alloc((size_t)NPAD * HEADS * 4);
    float* al_d     = (float*)alloc((size_t)NPAD * HEADS * 4);
    int*   counts   = (int*)alloc((size_t)N_NODES * 4);
    int*   offsets  = (int*)alloc((size_t)(N_NODES + 1) * 4);
    int*   cursor   = (int*)alloc((size_t)N_NODES * 4);
    int*   tmp      = (int*)alloc((size_t)N_NODES * 4);
    int*   partial  = (int*)alloc((size_t)SCAN_BLK * 4);
    int*   edge_src = (int*)alloc((size_t)EP * 4);
    float* pool     = (float*)alloc((size_t)G_B * HID * 4);
    float* pool_cnt = (float*)alloc((size_t)G_B * 4);

    // CSR build (once per launch; reused by all 3 layers)
    k_init <<<NBLK_SCAN, 256, 0, stream>>>(counts, cursor, pool, pool_cnt);
    k_count<<<(N_EDGES + 255) / 256, 256, 0, stream>>>(ei, counts);
    k_scan1<<<NBLK_SCAN, SCAN_BLK, 0, stream>>>(counts, tmp, partial);
    k_scan2<<<1, SCAN_BLK, 0, stream>>>(partial);
    k_scan3<<<NBLK_SCAN, 256, 0, stream>>>(tmp, counts, partial, offsets);
    k_fill <<<(EP + 255) / 256, 256, 0, stream>>>(ei, offsets, cursor, edge_src);

    // node embedding (writes all NPAD rows of h; tail rows harmless garbage)
    k_emb<<<NPAD / NT, 256, 0, stream>>>(x, W_emb, b_emb, h);

    // 3 GAT layers
    for (int l = 0; l < 3; l++) {
        k_z  <<<(NPAD / NT) * 4, 256, 0, stream>>>(h, W_gat + (size_t)l * HID * ZD,
                                                   att_src + (size_t)l * HEADS * HID,
                                                   att_dst + (size_t)l * HEADS * HID,
                                                   z, al_s, al_d);
        k_agg<<<N_NODES / 4, 256, 0, stream>>>(offsets, edge_src, al_s, al_d, z,
                                               b_gat + (size_t)l * HID, h);
    }

    // pooling + FC
    k_pool<<<NBLK_SCAN, 64, 0, stream>>>(h, batch, pool, pool_cnt);
    k_fc  <<<(OUT_F + 255) / 256, 256, 0, stream>>>(pool, pool_cnt, W_fc, b_fc, out);
}

// Round 5
// 666.159 us; speedup vs baseline: 1.4366x; 1.0046x over previous
//
#include <hip/hip_runtime.h>
#include <math.h>

#define N_NODES 50000
#define NPAD 50048               // 64 * 782, padded node count for tiled GEMMs
#define N_EDGES 500000
#define EP (N_EDGES + N_NODES)   // 550000
#define IN_F 128
#define HID 64
#define HEADS 4
#define ZD (HEADS * HID)         // 256
#define G_B 16
#define OUT_F 326000
#define NEG 0.2f
#define SCAN_BLK 256
#define NBLK_SCAN ((N_NODES + SCAN_BLK - 1) / SCAN_BLK)   // 196
#define CAP 64                   // LDS-stash cap per dst
#define EVS 72                   // per-head LDS stride
#define NT 64                    // node tile for GEMM kernels
#define KP 68                    // padded k-row stride (mult of 4 for b128)

// ---------------- init ----------------
__global__ void k_init(int* counts, int* cursor, float* pool, float* pool_cnt) {
    int i = blockIdx.x * 256 + threadIdx.x;
    if (i < N_NODES) { counts[i] = 1; cursor[i] = 0; }
    if (i < G_B * HID) pool[i] = 0.f;
    if (i < G_B) pool_cnt[i] = 0.f;
}

__global__ void k_count(const int* __restrict__ ei, int* __restrict__ counts) {
    int i = blockIdx.x * 256 + threadIdx.x;
    if (i < N_EDGES) atomicAdd(&counts[ei[N_EDGES + i]], 1);
}

__global__ void k_scan1(const int* __restrict__ counts, int* __restrict__ tmp,
                        int* __restrict__ partial) {
    __shared__ int s[SCAN_BLK];
    int t = threadIdx.x;
    int i = blockIdx.x * SCAN_BLK + t;
    int v = (i < N_NODES) ? counts[i] : 0;
    s[t] = v;
    __syncthreads();
    for (int off = 1; off < SCAN_BLK; off <<= 1) {
        int a = (t >= off) ? s[t - off] : 0;
        __syncthreads();
        s[t] += a;
        __syncthreads();
    }
    if (i < N_NODES) tmp[i] = s[t];
    if (t == SCAN_BLK - 1) partial[blockIdx.x] = s[t];
}

__global__ void k_scan2(int* partial) {
    __shared__ int s[SCAN_BLK];
    int t = threadIdx.x;
    int v = (t < NBLK_SCAN) ? partial[t] : 0;
    s[t] = v;
    __syncthreads();
    for (int off = 1; off < SCAN_BLK; off <<= 1) {
        int a = (t >= off) ? s[t - off] : 0;
        __syncthreads();
        s[t] += a;
        __syncthreads();
    }
    if (t < NBLK_SCAN) partial[t] = s[t] - v;   // exclusive
}

__global__ void k_scan3(const int* __restrict__ tmp, const int* __restrict__ counts,
                        const int* __restrict__ partial, int* __restrict__ offsets) {
    int i = blockIdx.x * 256 + threadIdx.x;
    if (i < N_NODES) offsets[i] = tmp[i] - counts[i] + partial[i >> 8];
    if (i == 0) offsets[N_NODES] = EP;
}

__global__ void k_fill(const int* __restrict__ ei, const int* __restrict__ offsets,
                       int* __restrict__ cursor, int* __restrict__ edge_src) {
    int i = blockIdx.x * 256 + threadIdx.x;
    if (i >= EP) return;
    int s, d;
    if (i < N_EDGES) { s = ei[i]; d = ei[N_EDGES + i]; }
    else             { s = d = i - N_EDGES; }
    int pos = offsets[d] + atomicAdd(&cursor[d], 1);
    edge_src[pos] = s;
}

// ---------------- node embedding: LDS-LDS 4x4 register-tile GEMM ----------------
// 64 nodes x 64 cols per block; K=128 chunked in two 64-k passes.
__global__ __launch_bounds__(256) void k_emb(const float* __restrict__ x,
                                             const float* __restrict__ W,
                                             const float* __restrict__ b,
                                             float* __restrict__ h) {
    __shared__ float xT[NT * KP];        // [k][node] 17408 B
    __shared__ float ws[NT * KP];        // [k][col]  17408 B
    int t = threadIdx.x;
    int n0 = blockIdx.x * NT;
    int w = t >> 6, l = t & 63;
    int tn = (w * 4 + (l >> 4)) * 4;     // node base
    int tc = (l & 15) * 4;               // col base

    float4 a0 = {0,0,0,0}, a1 = {0,0,0,0}, a2 = {0,0,0,0}, a3 = {0,0,0,0};
    for (int kc = 0; kc < IN_F; kc += NT) {
        if (kc) __syncthreads();         // drain previous chunk's reads
        // stage x transposed
        {
            int r = t >> 2, s = t & 3;
            int rg = n0 + r; if (rg >= N_NODES) rg = N_NODES - 1;
            #pragma unroll
            for (int i = 0; i < 4; i++) {
                int q0 = (i * 4 + s) * 4;
                float4 v = *(const float4*)&x[(size_t)rg * IN_F + kc + q0];
                xT[(q0 + 0) * KP + r] = v.x;
                xT[(q0 + 1) * KP + r] = v.y;
                xT[(q0 + 2) * KP + r] = v.z;
                xT[(q0 + 3) * KP + r] = v.w;
            }
        }
        // stage W chunk [64k][64c]
        #pragma unroll
        for (int i = 0; i < 4; i++) {
            int idx = i * 256 + t;
            int k = idx >> 4, cq = (idx & 15) * 4;
            float4 v = *(const float4*)&W[(size_t)(kc + k) * HID + cq];
            *(float4*)&ws[k * KP + cq] = v;
        }
        __syncthreads();
        for (int k = 0; k < NT; k++) {
            float4 hn = *(const float4*)&xT[k * KP + tn];
            float4 wc = *(const float4*)&ws[k * KP + tc];
            a0.x += hn.x * wc.x; a0.y += hn.x * wc.y; a0.z += hn.x * wc.z; a0.w += hn.x * wc.w;
            a1.x += hn.y * wc.x; a1.y += hn.y * wc.y; a1.z += hn.y * wc.z; a1.w += hn.y * wc.w;
            a2.x += hn.z * wc.x; a2.y += hn.z * wc.y; a2.z += hn.z * wc.z; a2.w += hn.z * wc.w;
            a3.x += hn.w * wc.x; a3.y += hn.w * wc.y; a3.z += hn.w * wc.z; a3.w += hn.w * wc.w;
        }
    }
    float4 bv = *(const float4*)&b[tc];
    a0.x += bv.x; a0.y += bv.y; a0.z += bv.z; a0.w += bv.w;
    a1.x += bv.x; a1.y += bv.y; a1.z += bv.z; a1.w += bv.w;
    a2.x += bv.x; a2.y += bv.y; a2.z += bv.z; a2.w += bv.w;
    a3.x += bv.x; a3.y += bv.y; a3.z += bv.z; a3.w += bv.w;
    *(float4*)&h[(size_t)(n0 + tn + 0) * HID + tc] = a0;
    *(float4*)&h[(size_t)(n0 + tn + 1) * HID + tc] = a1;
    *(float4*)&h[(size_t)(n0 + tn + 2) * HID + tc] = a2;
    *(float4*)&h[(size_t)(n0 + tn + 3) * HID + tc] = a3;
}

// ---------------- z = h @ W + fused attention logits --------------
// grid = 782 tiles x 4 col-groups (cg == head). LDS-LDS 4x4 tile GEMM.
__global__ __launch_bounds__(256) void k_z(const float* __restrict__ h,
                                           const float* __restrict__ W,
                                           const float* __restrict__ a_src,
                                           const float* __restrict__ a_dst,
                                           float* __restrict__ z,
                                           float* __restrict__ al_s,
                                           float* __restrict__ al_d) {
    __shared__ float hsT[HID * KP];      // [k][node] 17408 B
    __shared__ float ws[HID * KP];       // [k][col]  17408 B
    __shared__ float pp[2 * NT * 17];    // att partials [2][node][17] 8704 B
    int t = threadIdx.x;
    int tile = blockIdx.x >> 2;
    int cg = blockIdx.x & 3;             // head
    int n0 = tile * NT;

    // stage h transposed
    {
        int r = t >> 2, s = t & 3;
        #pragma unroll
        for (int i = 0; i < 4; i++) {
            int q0 = (i * 4 + s) * 4;
            float4 v = *(const float4*)&h[(size_t)(n0 + r) * HID + q0];
            hsT[(q0 + 0) * KP + r] = v.x;
            hsT[(q0 + 1) * KP + r] = v.y;
            hsT[(q0 + 2) * KP + r] = v.z;
            hsT[(q0 + 3) * KP + r] = v.w;
        }
    }
    // stage W block [64k][64c] for this head
    #pragma unroll
    for (int i = 0; i < 4; i++) {
        int idx = i * 256 + t;
        int k = idx >> 4, cq = (idx & 15) * 4;
        float4 v = *(const float4*)&W[(size_t)k * ZD + cg * 64 + cq];
        *(float4*)&ws[k * KP + cq] = v;
    }
    __syncthreads();

    int w = t >> 6, l = t & 63;
    int tn = (w * 4 + (l >> 4)) * 4;
    int tc = (l & 15) * 4;
    float4 a0 = {0,0,0,0}, a1 = {0,0,0,0}, a2 = {0,0,0,0}, a3 = {0,0,0,0};
    for (int k = 0; k < HID; k++) {
        float4 hn = *(const float4*)&hsT[k * KP + tn];
        float4 wc = *(const float4*)&ws[k * KP + tc];
        a0.x += hn.x * wc.x; a0.y += hn.x * wc.y; a0.z += hn.x * wc.z; a0.w += hn.x * wc.w;
        a1.x += hn.y * wc.x; a1.y += hn.y * wc.y; a1.z += hn.y * wc.z; a1.w += hn.y * wc.w;
        a2.x += hn.z * wc.x; a2.y += hn.z * wc.y; a2.z += hn.z * wc.z; a2.w += hn.z * wc.w;
        a3.x += hn.w * wc.x; a3.y += hn.w * wc.y; a3.z += hn.w * wc.z; a3.w += hn.w * wc.w;
    }

    // attention logit partials: dot over this thread's 4 cols for its 4 nodes
    float4 as4 = *(const float4*)&a_src[cg * HID + tc];
    float4 ad4 = *(const float4*)&a_dst[cg * HID + tc];
    int tcI = l & 15;
    {
        float ps, pd;
        ps = a0.x*as4.x + a0.y*as4.y + a0.z*as4.z + a0.w*as4.w;
        pd = a0.x*ad4.x + a0.y*ad4.y + a0.z*ad4.z + a0.w*ad4.w;
        pp[(tn + 0) * 17 + tcI] = ps; pp[NT*17 + (tn + 0) * 17 + tcI] = pd;
        ps = a1.x*as4.x + a1.y*as4.y + a1.z*as4.z + a1.w*as4.w;
        pd = a1.x*ad4.x + a1.y*ad4.y + a1.z*ad4.z + a1.w*ad4.w;
        pp[(tn + 1) * 17 + tcI] = ps; pp[NT*17 + (tn + 1) * 17 + tcI] = pd;
        ps = a2.x*as4.x + a2.y*as4.y + a2.z*as4.z + a2.w*as4.w;
        pd = a2.x*ad4.x + a2.y*ad4.y + a2.z*ad4.z + a2.w*ad4.w;
        pp[(tn + 2) * 17 + tcI] = ps; pp[NT*17 + (tn + 2) * 17 + tcI] = pd;
        ps = a3.x*as4.x + a3.y*as4.y + a3.z*as4.z + a3.w*as4.w;
        pd = a3.x*ad4.x + a3.y*ad4.y + a3.z*ad4.z + a3.w*ad4.w;
        pp[(tn + 3) * 17 + tcI] = ps; pp[NT*17 + (tn + 3) * 17 + tcI] = pd;
    }

    // direct coalesced z stores (tc fast within wave -> 256 B segments)
    *(float4*)&z[(size_t)(n0 + tn + 0) * ZD + cg * 64 + tc] = a0;
    *(float4*)&z[(size_t)(n0 + tn + 1) * ZD + cg * 64 + tc] = a1;
    *(float4*)&z[(size_t)(n0 + tn + 2) * ZD + cg * 64 + tc] = a2;
    *(float4*)&z[(size_t)(n0 + tn + 3) * ZD + cg * 64 + tc] = a3;

    __syncthreads();
    if (t < NT) {
        float s1 = 0.f, s2 = 0.f;
        #pragma unroll
        for (int j = 0; j < 16; j++) {
            s1 += pp[t * 17 + j];
            s2 += pp[NT*17 + t * 17 + j];
        }
        al_s[(n0 + t) * HEADS + cg] = s1;
        al_d[(n0 + t) * HEADS + cg] = s2;
    }
}

__device__ __forceinline__ float lrelu(float v) { return v > 0.f ? v : NEG * v; }

// ---------------- fused softmax + aggregate: ONE WAVE PER DST ----------------
__global__ void k_agg(const int* __restrict__ offsets, const int* __restrict__ edge_src,
                      const float* __restrict__ al_s, const float* __restrict__ al_d,
                      const float* __restrict__ z, const float* __restrict__ b,
                      float* __restrict__ h) {
    __shared__ float evb[4][HEADS * EVS];   // per wave: per-head alpha stash
    __shared__ int   sb[4][CAP];            // per wave: src idx stash
    int t  = threadIdx.x;
    int w  = t >> 6;
    int l  = t & 63;
    int hd = l >> 4;
    int j  = l & 15;
    int d  = blockIdx.x * 4 + w;

    int start = __builtin_amdgcn_readfirstlane(offsets[d]);
    int end   = __builtin_amdgcn_readfirstlane(offsets[d + 1]);
    int deg   = end - start;
    float al_dd = al_d[d * HEADS + hd];

    // phase 1: per-lane online softmax over strided edges; stash src + ev
    float m = -INFINITY, ssum = 0.f;
    for (int i = start + j; i < end; i += 16) {
        int s = edge_src[i];
        int slot = i - start;
        if (hd == 0 && slot < CAP) sb[w][slot] = s;
        float ev = lrelu(al_s[s * HEADS + hd] + al_dd);
        if (slot < CAP) evb[w][hd * EVS + slot] = ev;
        float nm = fmaxf(m, ev);
        ssum = ssum * __expf(m - nm) + __expf(ev - nm);
        m = nm;
    }
    float M = m;
    for (int o = 8; o > 0; o >>= 1) M = fmaxf(M, __shfl_xor(M, o));
    float S = ssum * __expf(m - M);
    for (int o = 8; o > 0; o >>= 1) S += __shfl_xor(S, o);
    float inv = 1.f / (S + 1e-16f);
    int stop = deg < CAP ? deg : CAP;
    for (int slot = j; slot < stop; slot += 16)
        evb[w][hd * EVS + slot] = __expf(evb[w][hd * EVS + slot] - M) * inv;

    // phase 2: weighted float4 gather of full z rows, x4 unrolled
    int zoff = l * 4;
    float4 acc = {0.f, 0.f, 0.f, 0.f};
    if (deg <= CAP) {
        float4 a1 = {0,0,0,0}, a2 = {0,0,0,0}, a3 = {0,0,0,0};
        int slot = 0;
        for (; slot + 4 <= deg; slot += 4) {
            int s0 = sb[w][slot],     s1 = sb[w][slot + 1];
            int s2 = sb[w][slot + 2], s3 = sb[w][slot + 3];
            float w0 = evb[w][hd * EVS + slot];
            float w1 = evb[w][hd * EVS + slot + 1];
            float w2 = evb[w][hd * EVS + slot + 2];
            float w3 = evb[w][hd * EVS + slot + 3];
            float4 z0 = *(const float4*)&z[(size_t)s0 * ZD + zoff];
            float4 z1 = *(const float4*)&z[(size_t)s1 * ZD + zoff];
            float4 z2 = *(const float4*)&z[(size_t)s2 * ZD + zoff];
            float4 z3 = *(const float4*)&z[(size_t)s3 * ZD + zoff];
            acc.x += w0 * z0.x; acc.y += w0 * z0.y; acc.z += w0 * z0.z; acc.w += w0 * z0.w;
            a1.x  += w1 * z1.x; a1.y  += w1 * z1.y; a1.z  += w1 * z1.z; a1.w  += w1 * z1.w;
            a2.x  += w2 * z2.x; a2.y  += w2 * z2.y; a2.z  += w2 * z2.z; a2.w  += w2 * z2.w;
            a3.x  += w3 * z3.x; a3.y  += w3 * z3.y; a3.z  += w3 * z3.z; a3.w  += w3 * z3.w;
        }
        for (; slot < deg; slot++) {
            int s0 = sb[w][slot];
            float w0 = evb[w][hd * EVS + slot];
            float4 z0 = *(const float4*)&z[(size_t)s0 * ZD + zoff];
            acc.x += w0 * z0.x; acc.y += w0 * z0.y; acc.z += w0 * z0.z; acc.w += w0 * z0.w;
        }
        acc.x += a1.x + a2.x + a3.x;
        acc.y += a1.y + a2.y + a3.y;
        acc.z += a1.z + a2.z + a3.z;
        acc.w += a1.w + a2.w + a3.w;
    } else {
        for (int i = start; i < end; i++) {
            int s = __builtin_amdgcn_readfirstlane(edge_src[i]);
            float ev = lrelu(al_s[s * HEADS + hd] + al_dd);
            float alpha = __expf(ev - M) * inv;
            float4 zr = *(const float4*)&z[(size_t)s * ZD + zoff];
            acc.x += alpha * zr.x; acc.y += alpha * zr.y;
            acc.z += alpha * zr.z; acc.w += alpha * zr.w;
        }
    }
    // head mean across the 4 head groups
    acc.x += __shfl_xor(acc.x, 16); acc.y += __shfl_xor(acc.y, 16);
    acc.z += __shfl_xor(acc.z, 16); acc.w += __shfl_xor(acc.w, 16);
    acc.x += __shfl_xor(acc.x, 32); acc.y += __shfl_xor(acc.y, 32);
    acc.z += __shfl_xor(acc.z, 32); acc.w += __shfl_xor(acc.w, 32);
    if (l < 16) {
        float4 bv = *(const float4*)&b[l * 4];
        float4 r;
        r.x = fmaxf(acc.x * 0.25f + bv.x, 0.f);
        r.y = fmaxf(acc.y * 0.25f + bv.y, 0.f);
        r.z = fmaxf(acc.z * 0.25f + bv.z, 0.f);
        r.w = fmaxf(acc.w * 0.25f + bv.w, 0.f);
        *(float4*)&h[(size_t)d * HID + l * 4] = r;
    }
}

// ---------------- global mean pool (batch is sorted) ----------------
__global__ void k_pool(const float* __restrict__ h, const int* __restrict__ batch,
                       float* __restrict__ pool, float* __restrict__ pool_cnt) {
    int f = threadIdx.x;           // 64 threads
    int n0 = blockIdx.x * 256;
    int n1 = n0 + 256;
    if (n1 > N_NODES) n1 = N_NODES;
    if (n0 >= n1) return;
    int curg = batch[n0];
    float acc = 0.f;
    int cnt = 0;
    for (int n = n0; n < n1; n++) {
        int g = batch[n];
        if (g != curg) {
            atomicAdd(&pool[curg * HID + f], acc);
            if (f == 0) atomicAdd(&pool_cnt[curg], (float)cnt);
            acc = 0.f; cnt = 0; curg = g;
        }
        acc += h[n * HID + f];
        cnt++;
    }
    atomicAdd(&pool[curg * HID + f], acc);
    if (f == 0) atomicAdd(&pool_cnt[curg], (float)cnt);
}

// ---------------- final FC: out = hg @ W_fc + b_fc (float4) ----------------
__global__ void k_fc(const float* __restrict__ pool, const float* __restrict__ pool_cnt,
                     const float* __restrict__ W_fc, const float* __restrict__ b_fc,
                     float* __restrict__ out) {
    __shared__ float hg[G_B * HID];
    int t = threadIdx.x;
    for (int i = t; i < G_B * HID; i += 256)
        hg[i] = pool[i] / fmaxf(pool_cnt[i / HID], 1.f);
    __syncthreads();
    int o4 = blockIdx.x * 256 + t;
    if (o4 >= OUT_F / 4) return;
    int o = o4 * 4;
    float4 acc[G_B];
    float4 bo = *(const float4*)&b_fc[o];
    #pragma unroll
    for (int g = 0; g < G_B; g++) acc[g] = bo;
    for (int k = 0; k < HID; k++) {
        float4 wv = *(const float4*)&W_fc[(size_t)k * OUT_F + o];
        #pragma unroll
        for (int g = 0; g < G_B; g++) {
            float hv = hg[g * HID + k];
            acc[g].x += hv * wv.x; acc[g].y += hv * wv.y;
            acc[g].z += hv * wv.z; acc[g].w += hv * wv.w;
        }
    }
    #pragma unroll
    for (int g = 0; g < G_B; g++) *(float4*)&out[(size_t)g * OUT_F + o] = acc[g];
}

extern "C" void kernel_launch(void* const* d_in, const int* in_sizes, int n_in,
                              void* d_out, int out_size, void* d_ws, size_t ws_size,
                              hipStream_t stream) {
    const float* x       = (const float*)d_in[0];
    const int*   ei      = (const int*)d_in[1];
    // d_in[2] edge_attr: unused by the reference forward
    const int*   batch   = (const int*)d_in[3];
    const float* W_emb   = (const float*)d_in[4];
    const float* b_emb   = (const float*)d_in[5];
    const float* W_gat   = (const float*)d_in[6];
    const float* att_src = (const float*)d_in[7];
    const float* att_dst = (const float*)d_in[8];
    const float* b_gat   = (const float*)d_in[9];
    const float* W_fc    = (const float*)d_in[10];
    const float* b_fc    = (const float*)d_in[11];
    float* out = (float*)d_out;

    char* p = (char*)d_ws;
    auto alloc = [&](size_t bytes) -> void* {
        void* r = (void*)p;
        p += (bytes + 255) & ~(size_t)255;
        return r;
    };
    float* h        = (float*)alloc((size_t)NPAD * HID * 4);
    float* z        = (float*)alloc((size_t)NPAD * ZD * 4);
    float* al_s     = (float*)alloc((size_t)NPAD * HEADS * 4);
    float* al_d     = (float*)alloc((size_t)NPAD * HEADS * 4);
    int*   counts   = (int*)alloc((size_t)N_NODES * 4);
    int*   offsets  = (int*)alloc((size_t)(N_NODES + 1) * 4);
    int*   cursor   = (int*)alloc((size_t)N_NODES * 4);
    int*   tmp      = (int*)alloc((size_t)N_NODES * 4);
    int*   partial  = (int*)alloc((size_t)SCAN_BLK * 4);
    int*   edge_src = (int*)alloc((size_t)EP * 4);
    float* pool     = (float*)alloc((size_t)G_B * HID * 4);
    float* pool_cnt = (float*)alloc((size_t)G_B * 4);

    // CSR build (once per launch; reused by all 3 layers)
    k_init <<<NBLK_SCAN, 256, 0, stream>>>(counts, cursor, pool, pool_cnt);
    k_count<<<(N_EDGES + 255) / 256, 256, 0, stream>>>(ei, counts);
    k_scan1<<<NBLK_SCAN, SCAN_BLK, 0, stream>>>(counts, tmp, partial);
    k_scan2<<<1, SCAN_BLK, 0, stream>>>(partial);
    k_scan3<<<NBLK_SCAN, 256, 0, stream>>>(tmp, counts, partial, offsets);
    k_fill <<<(EP + 255) / 256, 256, 0, stream>>>(ei, offsets, cursor, edge_src);

    // node embedding (writes all NPAD rows of h; tail rows harmless)
    k_emb<<<NPAD / NT, 256, 0, stream>>>(x, W_emb, b_emb, h);

    // 3 GAT layers
    for (int l = 0; l < 3; l++) {
        k_z  <<<(NPAD / NT) * 4, 256, 0, stream>>>(h, W_gat + (size_t)l * HID * ZD,
                                                   att_src + (size_t)l * HEADS * HID,
                                                   att_dst + (size_t)l * HEADS * HID,
                                                   z, al_s, al_d);
        k_agg<<<N_NODES / 4, 256, 0, stream>>>(offsets, edge_src, al_s, al_d, z,
                                               b_gat + (size_t)l * HID, h);
    }

    // pooling + FC
    k_pool<<<NBLK_SCAN, 64, 0, stream>>>(h, batch, pool, pool_cnt);
    k_fc  <<<(OUT_F / 4 + 255) / 256, 256, 0, stream>>>(pool, pool_cnt, W_fc, b_fc, out);
}